// Round 8
// baseline (793.074 us; speedup 1.0000x reference)
//
#include <hip/hip_runtime.h>
#include <stdint.h>

#define NE 64
#define NT 2048
#define NH 512
#define NI 1024

typedef __attribute__((ext_vector_type(8))) short bf16x8;
typedef __attribute__((ext_vector_type(4))) float f32x4;

typedef const __attribute__((address_space(1))) void* gptr1_t;
typedef __attribute__((address_space(3))) void* lptr3_t;
#define GLOAD16(g, l) \
  __builtin_amdgcn_global_load_lds((gptr1_t)(const void*)(g), (lptr3_t)(void*)(l), 16, 0, 0)

static __device__ __forceinline__ uint16_t f2bf(float f) {
  uint32_t u = __builtin_bit_cast(uint32_t, f);
  u += 0x7fffu + ((u >> 16) & 1u);
  return (uint16_t)(u >> 16);
}

static __device__ __forceinline__ float gelu_erf(float v) {
  return 0.5f * v * (1.0f + erff(v * 0.7071067811865475f));
}

// ---------------------------------------------------------------------------
// cast_x: x[t_start+t][e][:] f32 -> xB[e][t][:] bf16 (coalesced relayout)
// ---------------------------------------------------------------------------
__global__ __launch_bounds__(256)
void cast_x(const float* __restrict__ x, uint16_t* __restrict__ xB,
            int t_start, int S) {
  const int total = S * NE * (NH / 8);
  for (int c = blockIdx.x * 256 + threadIdx.x; c < total; c += gridDim.x * 256) {
    const int hb = c & 63;
    const int e = (c >> 6) & 63;
    const int t = c >> 12;
    const float* ip = x + ((size_t)(t_start + t) * NE + e) * NH + (hb << 3);
    const f32x4 v0 = *(const f32x4*)ip;
    const f32x4 v1 = *(const f32x4*)(ip + 4);
    bf16x8 w;
#pragma unroll
    for (int u = 0; u < 4; ++u) {
      w[u] = (short)f2bf(v0[u]);
      w[u + 4] = (short)f2bf(v1[u]);
    }
    *(bf16x8*)&xB[((size_t)e * S + t) * NH + (hb << 3)] = w;
  }
}

// ---------------------------------------------------------------------------
// transpose + cast: in[e][K][N] f32 -> out[e][N][K] bf16, 64x64 tiles
// ---------------------------------------------------------------------------
__global__ __launch_bounds__(256)
void conv_tr(const float* __restrict__ in, uint16_t* __restrict__ out, int K, int N) {
  const int e = blockIdx.x;
  const int k0 = blockIdx.y << 6;
  const int n0 = blockIdx.z << 6;
  __shared__ uint16_t t[64][72];
  const int tid = threadIdx.x;
  const int r = tid >> 2;
  const int c0 = (tid & 3) << 4;
  const float* ip = in + ((size_t)e * K + k0 + r) * N + n0 + c0;
#pragma unroll
  for (int j = 0; j < 16; j += 4) {
    f32x4 v = *(const f32x4*)(ip + j);
#pragma unroll
    for (int u = 0; u < 4; ++u) t[c0 + j + u][r] = f2bf(v[u]);
  }
  __syncthreads();
  uint16_t* op = out + ((size_t)e * N + n0 + r) * K + k0 + c0;
  *(bf16x8*)op = *(const bf16x8*)&t[r][c0];
  *(bf16x8*)(op + 8) = *(const bf16x8*)&t[r][c0 + 8];
}

// ---------------------------------------------------------------------------
// 128x128x64-tile grouped GEMM, B-direct variant.
// A[e]: [Ts][STR] bf16 row-major -> staged via global_load_lds with
//   XOR-swizzled SOURCE (LDS dest linear); LDS elem (r,k) at
//   r*64 + ((k>>3)^(r&7))*8 + (k&7). 16 KiB LDS total (A only).
// B[e]: [NTILES*128][STR] bf16 row-major (n-major, k-contiguous) -> each lane
//   loads its MFMA B-fragment DIRECTLY from global (16 B, L2-resident
//   weights), double-buffered in registers; prefetch for tile it+1 issued
//   right after the stage barrier so the pre-barrier vmcnt(0) drain next
//   iteration never waits on it (full compute phase of slack).
// 4 waves (2x2), 4x4 16x16x32 MFMA per wave. 2 barriers per K-step (m97).
// ---------------------------------------------------------------------------
template <int KIT, int NTILES, int STR, bool GELU>
__global__ __launch_bounds__(256, 3)
void k_mm(const uint16_t* __restrict__ Ag, const uint16_t* __restrict__ Bg,
          void* __restrict__ outp, int t_start, int Ts) {
  const int Mt = Ts >> 7;
  const int nwg = gridDim.x;  // divisible by 8
  const int wid = (blockIdx.x & 7) * (nwg >> 3) + (blockIdx.x >> 3);
  const int bn = wid & (NTILES - 1);
  const int bm = (wid / NTILES) % Mt;
  const int be = wid / (NTILES * Mt);
  const int t0 = bm << 7, n0 = bn << 7;

  __shared__ __align__(16) uint16_t As[8192];  // 128 x 64 bf16

  const int tid = threadIdx.x, lane = tid & 63;
  const int wy = (tid >> 7) & 1, wx = (tid >> 6) & 1;
  const int fr = lane & 15, fq = lane >> 4;

  const uint16_t* Abase = Ag + ((size_t)be * Ts + t0) * STR;
  const uint16_t* Bbase = Bg + ((size_t)be * (NTILES * 128) + n0) * STR;

  // A staging: 4 chunks/thread, swizzled global source, linear LDS dest
  int aoff[4], ldsOff[4];
#pragma unroll
  for (int s = 0; s < 4; ++s) {
    const int c = (s << 8) + tid;
    const int rr = c >> 3, kgs = c & 7;
    aoff[s] = rr * STR + ((kgs ^ (rr & 7)) << 3);
    ldsOff[s] = c << 4;
  }

  // B fragment base pointers: col = n0-local row of B, k-contig
  const uint16_t* bp[4];
#pragma unroll
  for (int ni = 0; ni < 4; ++ni)
    bp[ni] = Bbase + (size_t)((wx << 6) + (ni << 4) + fr) * STR + (fq << 3);

  f32x4 acc[4][4];
#pragma unroll
  for (int i = 0; i < 4; ++i)
#pragma unroll
    for (int j = 0; j < 4; ++j) acc[i][j] = (f32x4){0.f, 0.f, 0.f, 0.f};

  bf16x8 b0[4][2], b1[4][2];

  auto stageA = [&](int it) {
#pragma unroll
    for (int s = 0; s < 4; ++s)
      GLOAD16(Abase + (it << 6) + aoff[s], (char*)As + ldsOff[s]);
  };
#define LOADB(buf, it)                                                        \
  _Pragma("unroll") for (int ni = 0; ni < 4; ++ni)                            \
      _Pragma("unroll") for (int ks = 0; ks < 2; ++ks)                        \
          buf[ni][ks] = *(const bf16x8*)(bp[ni] + ((it) << 6) + (ks << 5));
#define COMPUTE(buf)                                                          \
  _Pragma("unroll") for (int ks = 0; ks < 2; ++ks) {                          \
    const int kg = (ks << 2) + fq;                                            \
    bf16x8 af[4];                                                             \
    _Pragma("unroll") for (int mi = 0; mi < 4; ++mi) {                        \
      const int row = (wy << 6) + (mi << 4) + fr;                             \
      af[mi] = *(const bf16x8*)&As[(row << 6) + ((kg ^ (row & 7)) << 3)];     \
    }                                                                         \
    _Pragma("unroll") for (int mi = 0; mi < 4; ++mi)                          \
        _Pragma("unroll") for (int ni = 0; ni < 4; ++ni)                      \
            acc[mi][ni] = __builtin_amdgcn_mfma_f32_16x16x32_bf16(            \
                af[mi], buf[ni][ks], acc[mi][ni], 0, 0, 0);                   \
  }

  LOADB(b0, 0);
  for (int it = 0; it < KIT; it += 2) {
    // even tile: compute with b0, prefetch b1
    __syncthreads();  // all waves done reading As (prev tile)
    stageA(it);
    __syncthreads();  // vmcnt(0)+barrier: As ready
    LOADB(b1, it + 1);  // issued post-barrier; consumed next sub-iter
    COMPUTE(b0);
    // odd tile: compute with b1, prefetch b0
    __syncthreads();
    stageA(it + 1);
    __syncthreads();
    if (it + 2 < KIT) LOADB(b0, it + 2);
    COMPUTE(b1);
  }
#undef LOADB
#undef COMPUTE

  if constexpr (GELU) {
    uint16_t* hp = (uint16_t*)outp;
#pragma unroll
    for (int mi = 0; mi < 4; ++mi) {
#pragma unroll
      for (int ni = 0; ni < 4; ++ni) {
        const int col = n0 + (wx << 6) + (ni << 4) + fr;
#pragma unroll
        for (int j = 0; j < 4; ++j) {
          const int r = t0 + (wy << 6) + (mi << 4) + (fq << 2) + j;
          hp[((size_t)be * Ts + r) * NI + col] = f2bf(gelu_erf(acc[mi][ni][j]));
        }
      }
    }
  } else {
    float* op = (float*)outp;
#pragma unroll
    for (int mi = 0; mi < 4; ++mi) {
#pragma unroll
      for (int ni = 0; ni < 4; ++ni) {
        const int col = n0 + (wx << 6) + (ni << 4) + fr;
#pragma unroll
        for (int j = 0; j < 4; ++j) {
          const int r = t0 + (wy << 6) + (mi << 4) + (fq << 2) + j;
          op[((size_t)(t_start + r) * NE + be) * NH + col] = acc[mi][ni][j];
        }
      }
    }
  }
}

extern "C" void kernel_launch(void* const* d_in, const int* in_sizes, int n_in,
                              void* d_out, int out_size, void* d_ws, size_t ws_size,
                              hipStream_t stream) {
  const float* x = (const float*)d_in[0];   // [T, E, H] fp32
  const float* wi = (const float*)d_in[1];  // [E, H, I] fp32
  const float* wo = (const float*)d_in[2];  // [E, I, H] fp32
  float* out = (float*)d_out;

  // ws: wiB bf16 [E][I][H] (64MiB) | woB bf16 [E][H][I] (64MiB) | xB | h
  uint16_t* wiB = (uint16_t*)d_ws;
  uint16_t* woB = (uint16_t*)((char*)d_ws + 67108864);
  char* rest = (char*)d_ws + 134217728;

  const size_t perRow = (size_t)NE * NH * 2 + (size_t)NE * NI * 2;  // 192 KiB
  size_t avail = (ws_size > 134217728u) ? ws_size - 134217728u : 0;
  int Ts = (int)(avail / perRow);
  Ts &= ~127;
  if (Ts > NT) Ts = NT;
  if (Ts < 128) Ts = 128;

  hipLaunchKernelGGL(conv_tr, dim3(NE, NH / 64, NI / 64), dim3(256), 0, stream,
                     wi, wiB, NH, NI);
  hipLaunchKernelGGL(conv_tr, dim3(NE, NI / 64, NH / 64), dim3(256), 0, stream,
                     wo, woB, NI, NH);

  for (int ts = 0; ts < NT; ts += Ts) {
    int cur = NT - ts;
    if (cur > Ts) cur = Ts;
    const int Mt = cur >> 7;
    uint16_t* xB = (uint16_t*)rest;
    uint16_t* h = (uint16_t*)(rest + (size_t)NE * cur * NH * 2);
    const int castGrid = (cur * NE * (NH / 8) + 255) / 256;
    hipLaunchKernelGGL(cast_x, dim3(castGrid < 2048 ? castGrid : 2048), dim3(256),
                       0, stream, x, xB, ts, cur);
    hipLaunchKernelGGL((k_mm<8, 8, NH, true>), dim3(Mt * 8 * NE), dim3(256),
                       0, stream, xB, wiB, (void*)h, 0, cur);
    hipLaunchKernelGGL((k_mm<16, 4, NI, false>), dim3(Mt * 4 * NE), dim3(256),
                       0, stream, h, woB, (void*)out, ts, cur);
  }
}

// Round 9
// 678.549 us; speedup vs baseline: 1.1688x; 1.1688x over previous
//
#include <hip/hip_runtime.h>
#include <stdint.h>

#define NE 64
#define NT 2048
#define NH 512
#define NI 1024

typedef __attribute__((ext_vector_type(8))) short bf16x8;
typedef __attribute__((ext_vector_type(4))) float f32x4;

typedef const __attribute__((address_space(1))) void* gptr1_t;
typedef __attribute__((address_space(3))) void* lptr3_t;
#define GLOAD16(g, l) \
  __builtin_amdgcn_global_load_lds((gptr1_t)(const void*)(g), (lptr3_t)(void*)(l), 16, 0, 0)

static __device__ __forceinline__ uint16_t f2bf(float f) {
  uint32_t u = __builtin_bit_cast(uint32_t, f);
  u += 0x7fffu + ((u >> 16) & 1u);
  return (uint16_t)(u >> 16);
}

// tanh-form GELU: |gelu_tanh - gelu_erf| <= ~5e-4 (<< bf16 quantization of h).
// gelu = 0.5x(1+tanh(y)) = x - x/(exp(2y)+1), y = 0.79788456(x + 0.044715x^3).
static __device__ __forceinline__ float gelu_fast(float x) {
  const float x3 = x * x * x;
  const float twoy = 1.5957691216057308f * x + 0.07135481627f * x3;
  const float e = __expf(twoy);
  return x - x / (e + 1.0f);
}

// ---------------------------------------------------------------------------
// cast_x: x[t][e][:] f32 -> xB[e][t][:] bf16 (coalesced relayout, full T)
// ---------------------------------------------------------------------------
__global__ __launch_bounds__(256)
void cast_x(const float* __restrict__ x, uint16_t* __restrict__ xB) {
  const int total = NT * NE * (NH / 8);
  for (int c = blockIdx.x * 256 + threadIdx.x; c < total; c += gridDim.x * 256) {
    const int hb = c & 63;
    const int e = (c >> 6) & 63;
    const int t = c >> 12;
    const float* ip = x + ((size_t)t * NE + e) * NH + (hb << 3);
    const f32x4 v0 = *(const f32x4*)ip;
    const f32x4 v1 = *(const f32x4*)(ip + 4);
    bf16x8 w;
#pragma unroll
    for (int u = 0; u < 4; ++u) {
      w[u] = (short)f2bf(v0[u]);
      w[u + 4] = (short)f2bf(v1[u]);
    }
    *(bf16x8*)&xB[((size_t)e * NT + t) * NH + (hb << 3)] = w;
  }
}

// ---------------------------------------------------------------------------
// transpose + cast: in[e][K][N] f32 -> out[e][N][K] bf16, 64x64 tiles
// ---------------------------------------------------------------------------
__global__ __launch_bounds__(256)
void conv_tr(const float* __restrict__ in, uint16_t* __restrict__ out, int K, int N) {
  const int e = blockIdx.x;
  const int k0 = blockIdx.y << 6;
  const int n0 = blockIdx.z << 6;
  __shared__ uint16_t t[64][72];
  const int tid = threadIdx.x;
  const int r = tid >> 2;
  const int c0 = (tid & 3) << 4;
  const float* ip = in + ((size_t)e * K + k0 + r) * N + n0 + c0;
#pragma unroll
  for (int j = 0; j < 16; j += 4) {
    f32x4 v = *(const f32x4*)(ip + j);
#pragma unroll
    for (int u = 0; u < 4; ++u) t[c0 + j + u][r] = f2bf(v[u]);
  }
  __syncthreads();
  uint16_t* op = out + ((size_t)e * N + n0 + r) * K + k0 + c0;
  *(bf16x8*)op = *(const bf16x8*)&t[r][c0];
  *(bf16x8*)(op + 8) = *(const bf16x8*)&t[r][c0 + 8];
}

// ---------------------------------------------------------------------------
// GEMM1 + GELU: h[e,tl,i] = gelu( xB[e,ts+tl,:] . wi'[e,i,:] ), bf16 out.
// m97 structure (round-3 proven): 128x128x64 tile, single 32 KiB LDS buffer,
// 2 barriers/K-step, both operands via global_load_lds with XOR-swizzled
// SOURCE (LDS dest linear). LDS elem (r,k) at r*64 + ((k>>3)^(r&7))*8 + (k&7).
// ---------------------------------------------------------------------------
__global__ __launch_bounds__(256, 3)
void k_gemm1(const uint16_t* __restrict__ xB, const uint16_t* __restrict__ wiB,
             uint16_t* __restrict__ h, int t_start, int TsS) {
  const int Mt = TsS >> 7;
  const int nwg = gridDim.x;  // Mt*8*64, divisible by 8
  const int wid = (blockIdx.x & 7) * (nwg >> 3) + (blockIdx.x >> 3);
  const int bn = wid & 7;
  const int bm = (wid >> 3) % Mt;
  const int be = wid / (Mt << 3);
  const int t0 = bm << 7, n0 = bn << 7;  // t0 is slice-local

  __shared__ __align__(16) uint16_t As[8192];
  __shared__ __align__(16) uint16_t Bs[8192];

  const int tid = threadIdx.x, lane = tid & 63;
  const int wy = (tid >> 7) & 1, wx = (tid >> 6) & 1;

  const uint16_t* Abase = xB + ((size_t)be * NT + t_start + t0) * NH;
  const uint16_t* Bbase = wiB + ((size_t)be * NI + n0) * NH;

  int off[4], ldsOff[4];
#pragma unroll
  for (int s = 0; s < 4; ++s) {
    const int c = (s << 8) + tid;
    const int rr = c >> 3, kgs = c & 7;
    off[s] = (rr << 9) + ((kgs ^ (rr & 7)) << 3);  // row stride NH=512
    ldsOff[s] = c << 4;
  }

  f32x4 acc[4][4];
#pragma unroll
  for (int i = 0; i < 4; ++i)
#pragma unroll
    for (int j = 0; j < 4; ++j) acc[i][j] = (f32x4){0.f, 0.f, 0.f, 0.f};

  const int KIT = NH >> 6;  // 8
  for (int it = 0; it < KIT; ++it) {
    __syncthreads();
#pragma unroll
    for (int s = 0; s < 4; ++s)
      GLOAD16(Abase + (it << 6) + off[s], (char*)As + ldsOff[s]);
#pragma unroll
    for (int s = 0; s < 4; ++s)
      GLOAD16(Bbase + (it << 6) + off[s], (char*)Bs + ldsOff[s]);
    __syncthreads();
#pragma unroll
    for (int ks = 0; ks < 2; ++ks) {
      const int kg = (ks << 2) + (lane >> 4);
      bf16x8 af[4], bfr[4];
#pragma unroll
      for (int mi = 0; mi < 4; ++mi) {
        const int row = (wy << 6) + (mi << 4) + (lane & 15);
        af[mi] = *(const bf16x8*)&As[(row << 6) + ((kg ^ (row & 7)) << 3)];
      }
#pragma unroll
      for (int ni = 0; ni < 4; ++ni) {
        const int col = (wx << 6) + (ni << 4) + (lane & 15);
        bfr[ni] = *(const bf16x8*)&Bs[(col << 6) + ((kg ^ (col & 7)) << 3)];
      }
#pragma unroll
      for (int mi = 0; mi < 4; ++mi)
#pragma unroll
        for (int ni = 0; ni < 4; ++ni)
          acc[mi][ni] = __builtin_amdgcn_mfma_f32_16x16x32_bf16(
              af[mi], bfr[ni], acc[mi][ni], 0, 0, 0);
    }
  }

#pragma unroll
  for (int mi = 0; mi < 4; ++mi) {
#pragma unroll
    for (int ni = 0; ni < 4; ++ni) {
      const int col = n0 + (wx << 6) + (ni << 4) + (lane & 15);
#pragma unroll
      for (int j = 0; j < 4; ++j) {
        const int r = t0 + (wy << 6) + (mi << 4) + ((lane >> 4) << 2) + j;
        h[((size_t)be * TsS + r) * NI + col] = f2bf(gelu_fast(acc[mi][ni][j]));
      }
    }
  }
}

// ---------------------------------------------------------------------------
// GEMM2: out[ts+tl,e,hc] = h[e,tl,:] . wo'[e,hc,:], fp32 out (round-3 proven).
// ---------------------------------------------------------------------------
__global__ __launch_bounds__(256, 3)
void k_gemm2(const uint16_t* __restrict__ hA, const uint16_t* __restrict__ woB,
             float* __restrict__ out, int t_start, int TsS) {
  const int Mt = TsS >> 7;
  const int nwg = gridDim.x;  // Mt*4*64
  const int wid = (blockIdx.x & 7) * (nwg >> 3) + (blockIdx.x >> 3);
  const int bn = wid & 3;
  const int bm = (wid >> 2) % Mt;
  const int be = wid / (Mt << 2);
  const int t0 = bm << 7, n0 = bn << 7;

  __shared__ __align__(16) uint16_t As[8192];
  __shared__ __align__(16) uint16_t Bs[8192];

  const int tid = threadIdx.x, lane = tid & 63;
  const int wy = (tid >> 7) & 1, wx = (tid >> 6) & 1;

  const uint16_t* Abase = hA + ((size_t)be * TsS + t0) * NI;
  const uint16_t* Bbase = woB + ((size_t)be * NH + n0) * NI;

  int off[4], ldsOff[4];
#pragma unroll
  for (int s = 0; s < 4; ++s) {
    const int c = (s << 8) + tid;
    const int rr = c >> 3, kgs = c & 7;
    off[s] = (rr << 10) + ((kgs ^ (rr & 7)) << 3);  // row stride NI=1024
    ldsOff[s] = c << 4;
  }

  f32x4 acc[4][4];
#pragma unroll
  for (int i = 0; i < 4; ++i)
#pragma unroll
    for (int j = 0; j < 4; ++j) acc[i][j] = (f32x4){0.f, 0.f, 0.f, 0.f};

  const int KIT = NI >> 6;  // 16
  for (int it = 0; it < KIT; ++it) {
    __syncthreads();
#pragma unroll
    for (int s = 0; s < 4; ++s)
      GLOAD16(Abase + (it << 6) + off[s], (char*)As + ldsOff[s]);
#pragma unroll
    for (int s = 0; s < 4; ++s)
      GLOAD16(Bbase + (it << 6) + off[s], (char*)Bs + ldsOff[s]);
    __syncthreads();
#pragma unroll
    for (int ks = 0; ks < 2; ++ks) {
      const int kg = (ks << 2) + (lane >> 4);
      bf16x8 af[4], bfr[4];
#pragma unroll
      for (int mi = 0; mi < 4; ++mi) {
        const int row = (wy << 6) + (mi << 4) + (lane & 15);
        af[mi] = *(const bf16x8*)&As[(row << 6) + ((kg ^ (row & 7)) << 3)];
      }
#pragma unroll
      for (int ni = 0; ni < 4; ++ni) {
        const int col = (wx << 6) + (ni << 4) + (lane & 15);
        bfr[ni] = *(const bf16x8*)&Bs[(col << 6) + ((kg ^ (col & 7)) << 3)];
      }
#pragma unroll
      for (int mi = 0; mi < 4; ++mi)
#pragma unroll
        for (int ni = 0; ni < 4; ++ni)
          acc[mi][ni] = __builtin_amdgcn_mfma_f32_16x16x32_bf16(
              af[mi], bfr[ni], acc[mi][ni], 0, 0, 0);
    }
  }

#pragma unroll
  for (int mi = 0; mi < 4; ++mi) {
#pragma unroll
    for (int ni = 0; ni < 4; ++ni) {
      const int col = n0 + (wx << 6) + (ni << 4) + (lane & 15);
#pragma unroll
      for (int j = 0; j < 4; ++j) {
        const int r = t0 + (wy << 6) + (mi << 4) + ((lane >> 4) << 2) + j;
        out[((size_t)(t_start + r) * NE + be) * NH + col] = acc[mi][ni][j];
      }
    }
  }
}

extern "C" void kernel_launch(void* const* d_in, const int* in_sizes, int n_in,
                              void* d_out, int out_size, void* d_ws, size_t ws_size,
                              hipStream_t stream) {
  const float* x = (const float*)d_in[0];   // [T, E, H] fp32
  const float* wi = (const float*)d_in[1];  // [E, H, I] fp32
  const float* wo = (const float*)d_in[2];  // [E, I, H] fp32
  float* out = (float*)d_out;

  // ws: wiB [E][I][H] bf16 (64MiB) | woB [E][H][I] bf16 (64MiB) |
  //     xB [E][T][H] bf16 full (128MiB) | h slice [E][Ts][I] bf16 (64MiB @512)
  uint16_t* wiB = (uint16_t*)d_ws;
  uint16_t* woB = (uint16_t*)((char*)d_ws + 67108864);
  uint16_t* xB = (uint16_t*)((char*)d_ws + 134217728);
  uint16_t* h = (uint16_t*)((char*)d_ws + 134217728 + (size_t)NE * NT * NH * 2);

  // Ts=512: slice working set (weights 128MB + h 64MB) is L3-resident, so
  // gemm2 reads h from Infinity Cache and h writes mostly never reach HBM.
  const size_t fixed = 134217728u + (size_t)NE * NT * NH * 2;  // 256 MiB
  size_t avail = (ws_size > fixed) ? ws_size - fixed : 0;
  int Ts = (int)(avail / ((size_t)NE * NI * 2));
  if (Ts > 512) Ts = 512;
  Ts &= ~127;
  if (Ts < 128) Ts = 128;  // ws >= 512 MiB proven (rounds 3-6 ran Ts=2048)

  hipLaunchKernelGGL(conv_tr, dim3(NE, NH / 64, NI / 64), dim3(256), 0, stream,
                     wi, wiB, NH, NI);
  hipLaunchKernelGGL(conv_tr, dim3(NE, NI / 64, NH / 64), dim3(256), 0, stream,
                     wo, woB, NI, NH);
  hipLaunchKernelGGL(cast_x, dim3(2048), dim3(256), 0, stream, x, xB);

  for (int ts = 0; ts < NT; ts += Ts) {
    int cur = NT - ts;
    if (cur > Ts) cur = Ts;
    const int Mt = cur >> 7;
    hipLaunchKernelGGL(k_gemm1, dim3(Mt * 8 * NE), dim3(256), 0, stream,
                       xB, wiB, h, ts, cur);
    hipLaunchKernelGGL(k_gemm2, dim3(Mt * 4 * NE), dim3(256), 0, stream,
                       h, woB, out, ts, cur);
  }
}

// Round 10
// 563.202 us; speedup vs baseline: 1.4082x; 1.2048x over previous
//
#include <hip/hip_runtime.h>
#include <stdint.h>

#define NE 64
#define NT 2048
#define NH 512
#define NI 1024

typedef __attribute__((ext_vector_type(8))) short bf16x8;
typedef __attribute__((ext_vector_type(4))) float f32x4;

typedef const __attribute__((address_space(1))) void* gptr1_t;
typedef __attribute__((address_space(3))) void* lptr3_t;
#define GLOAD16(g, l) \
  __builtin_amdgcn_global_load_lds((gptr1_t)(const void*)(g), (lptr3_t)(void*)(l), 16, 0, 0)

static __device__ __forceinline__ uint16_t f2bf(float f) {
  uint32_t u = __builtin_bit_cast(uint32_t, f);
  u += 0x7fffu + ((u >> 16) & 1u);
  return (uint16_t)(u >> 16);
}

// tanh-form GELU: |gelu_tanh - gelu_erf| <= ~5e-4, << bf16 quantization of h.
// Verified r9: absmax identical to erf version (0.001953125).
static __device__ __forceinline__ float gelu_fast(float x) {
  const float x3 = x * x * x;
  const float twoy = 1.5957691216057308f * x + 0.07135481627f * x3;
  const float e = __expf(twoy);
  return x - x / (e + 1.0f);
}

// ---------------------------------------------------------------------------
// Fused prep (one launch):
//  blocks [0, 8192):        wi[e][512][1024] f32 -> wiB[e][n][k] bf16 (64x64 tr)
//  blocks [8192, 16384):    wo[e][1024][512] f32 -> woB[e][n][k] bf16
//  blocks [16384, 24576):   x[t][e][:] f32 -> xB[e][t][:] bf16 (4 chunks/thread)
// ---------------------------------------------------------------------------
__global__ __launch_bounds__(256)
void prep_fused(const float* __restrict__ wi, const float* __restrict__ wo,
                const float* __restrict__ x, uint16_t* __restrict__ wiB,
                uint16_t* __restrict__ woB, uint16_t* __restrict__ xB) {
  const int bid = blockIdx.x;
  const int tid = threadIdx.x;

  if (bid >= 16384) {  // cast_x section: 8192 blocks x 1024 chunks-of-8
    const int base = (bid - 16384) << 10;
#pragma unroll
    for (int k = 0; k < 4; ++k) {
      const int c = base + (k << 8) + tid;  // < 2048*64*64 = 8388608
      const int hb = c & 63;
      const int e = (c >> 6) & 63;
      const int t = c >> 12;
      const float* ip = x + ((size_t)t * NE + e) * NH + (hb << 3);
      const f32x4 v0 = *(const f32x4*)ip;
      const f32x4 v1 = *(const f32x4*)(ip + 4);
      bf16x8 w;
#pragma unroll
      for (int u = 0; u < 4; ++u) {
        w[u] = (short)f2bf(v0[u]);
        w[u + 4] = (short)f2bf(v1[u]);
      }
      *(bf16x8*)&xB[((size_t)e * NT + t) * NH + (hb << 3)] = w;
    }
    return;
  }

  // weight transpose sections
  const float* in;
  uint16_t* out;
  int K, N, k0, n0, e;
  if (bid < 8192) {
    e = bid >> 7;
    const int rem = bid & 127;
    k0 = (rem >> 4) << 6;  // K=512 -> 8 k-tiles
    n0 = (rem & 15) << 6;  // N=1024 -> 16 n-tiles
    in = wi; out = wiB; K = NH; N = NI;
  } else {
    const int id = bid - 8192;
    e = id >> 7;
    const int rem = id & 127;
    k0 = (rem >> 3) << 6;  // K=1024 -> 16 k-tiles
    n0 = (rem & 7) << 6;   // N=512 -> 8 n-tiles
    in = wo; out = woB; K = NI; N = NH;
  }
  __shared__ uint16_t t[64][72];
  const int r = tid >> 2;
  const int c0 = (tid & 3) << 4;
  const float* ip = in + ((size_t)e * K + k0 + r) * N + n0 + c0;
#pragma unroll
  for (int j = 0; j < 16; j += 4) {
    f32x4 v = *(const f32x4*)(ip + j);
#pragma unroll
    for (int u = 0; u < 4; ++u) t[c0 + j + u][r] = f2bf(v[u]);
  }
  __syncthreads();
  uint16_t* op = out + ((size_t)e * N + n0 + r) * K + k0 + c0;
  *(bf16x8*)op = *(const bf16x8*)&t[r][c0];
  *(bf16x8*)(op + 8) = *(const bf16x8*)&t[r][c0 + 8];
}

// ---------------------------------------------------------------------------
// GEMM1 + GELU: h[e,t,i] = gelu( xB[e,t,:] . wi'[e,i,:] ), bf16 out.
// m97 structure (round-3 proven): 128x128x64 tile, single 32 KiB LDS buffer,
// 2 barriers/K-step, both operands via global_load_lds with XOR-swizzled
// SOURCE (LDS dest linear). LDS elem (r,k) at r*64 + ((k>>3)^(r&7))*8 + (k&7).
// ---------------------------------------------------------------------------
__global__ __launch_bounds__(256, 3)
void k_gemm1(const uint16_t* __restrict__ xB, const uint16_t* __restrict__ wiB,
             uint16_t* __restrict__ h, int Ts) {
  const int Mt = Ts >> 7;
  const int nwg = gridDim.x;  // Mt*8*64, divisible by 8
  const int wid = (blockIdx.x & 7) * (nwg >> 3) + (blockIdx.x >> 3);
  const int bn = wid & 7;
  const int bm = (wid >> 3) % Mt;
  const int be = wid / (Mt << 3);
  const int t0 = bm << 7, n0 = bn << 7;

  __shared__ __align__(16) uint16_t As[8192];
  __shared__ __align__(16) uint16_t Bs[8192];

  const int tid = threadIdx.x, lane = tid & 63;
  const int wy = (tid >> 7) & 1, wx = (tid >> 6) & 1;

  const uint16_t* Abase = xB + ((size_t)be * Ts + t0) * NH;
  const uint16_t* Bbase = wiB + ((size_t)be * NI + n0) * NH;

  int off[4], ldsOff[4];
#pragma unroll
  for (int s = 0; s < 4; ++s) {
    const int c = (s << 8) + tid;
    const int rr = c >> 3, kgs = c & 7;
    off[s] = (rr << 9) + ((kgs ^ (rr & 7)) << 3);  // row stride NH=512
    ldsOff[s] = c << 4;
  }

  f32x4 acc[4][4];
#pragma unroll
  for (int i = 0; i < 4; ++i)
#pragma unroll
    for (int j = 0; j < 4; ++j) acc[i][j] = (f32x4){0.f, 0.f, 0.f, 0.f};

  const int KIT = NH >> 6;  // 8
  for (int it = 0; it < KIT; ++it) {
    __syncthreads();
#pragma unroll
    for (int s = 0; s < 4; ++s)
      GLOAD16(Abase + (it << 6) + off[s], (char*)As + ldsOff[s]);
#pragma unroll
    for (int s = 0; s < 4; ++s)
      GLOAD16(Bbase + (it << 6) + off[s], (char*)Bs + ldsOff[s]);
    __syncthreads();
#pragma unroll
    for (int ks = 0; ks < 2; ++ks) {
      const int kg = (ks << 2) + (lane >> 4);
      bf16x8 af[4], bfr[4];
#pragma unroll
      for (int mi = 0; mi < 4; ++mi) {
        const int row = (wy << 6) + (mi << 4) + (lane & 15);
        af[mi] = *(const bf16x8*)&As[(row << 6) + ((kg ^ (row & 7)) << 3)];
      }
#pragma unroll
      for (int ni = 0; ni < 4; ++ni) {
        const int col = (wx << 6) + (ni << 4) + (lane & 15);
        bfr[ni] = *(const bf16x8*)&Bs[(col << 6) + ((kg ^ (col & 7)) << 3)];
      }
#pragma unroll
      for (int mi = 0; mi < 4; ++mi)
#pragma unroll
        for (int ni = 0; ni < 4; ++ni)
          acc[mi][ni] = __builtin_amdgcn_mfma_f32_16x16x32_bf16(
              af[mi], bfr[ni], acc[mi][ni], 0, 0, 0);
    }
  }

#pragma unroll
  for (int mi = 0; mi < 4; ++mi) {
#pragma unroll
    for (int ni = 0; ni < 4; ++ni) {
      const int col = n0 + (wx << 6) + (ni << 4) + (lane & 15);
#pragma unroll
      for (int j = 0; j < 4; ++j) {
        const int r = t0 + (wy << 6) + (mi << 4) + ((lane >> 4) << 2) + j;
        h[((size_t)be * Ts + r) * NI + col] = f2bf(gelu_fast(acc[mi][ni][j]));
      }
    }
  }
}

// ---------------------------------------------------------------------------
// GEMM2: out[t,e,hc] = h[e,t,:] . wo'[e,hc,:], fp32 out (round-3 proven).
// ---------------------------------------------------------------------------
__global__ __launch_bounds__(256, 3)
void k_gemm2(const uint16_t* __restrict__ hA, const uint16_t* __restrict__ woB,
             float* __restrict__ out, int t_start, int Ts) {
  const int Mt = Ts >> 7;
  const int nwg = gridDim.x;  // Mt*4*64
  const int wid = (blockIdx.x & 7) * (nwg >> 3) + (blockIdx.x >> 3);
  const int bn = wid & 3;
  const int bm = (wid >> 2) % Mt;
  const int be = wid / (Mt << 2);
  const int t0 = bm << 7, n0 = bn << 7;

  __shared__ __align__(16) uint16_t As[8192];
  __shared__ __align__(16) uint16_t Bs[8192];

  const int tid = threadIdx.x, lane = tid & 63;
  const int wy = (tid >> 7) & 1, wx = (tid >> 6) & 1;

  const uint16_t* Abase = hA + ((size_t)be * Ts + t0) * NI;
  const uint16_t* Bbase = woB + ((size_t)be * NH + n0) * NI;

  int off[4], ldsOff[4];
#pragma unroll
  for (int s = 0; s < 4; ++s) {
    const int c = (s << 8) + tid;
    const int rr = c >> 3, kgs = c & 7;
    off[s] = (rr << 10) + ((kgs ^ (rr & 7)) << 3);  // row stride NI=1024
    ldsOff[s] = c << 4;
  }

  f32x4 acc[4][4];
#pragma unroll
  for (int i = 0; i < 4; ++i)
#pragma unroll
    for (int j = 0; j < 4; ++j) acc[i][j] = (f32x4){0.f, 0.f, 0.f, 0.f};

  const int KIT = NI >> 6;  // 16
  for (int it = 0; it < KIT; ++it) {
    __syncthreads();
#pragma unroll
    for (int s = 0; s < 4; ++s)
      GLOAD16(Abase + (it << 6) + off[s], (char*)As + ldsOff[s]);
#pragma unroll
    for (int s = 0; s < 4; ++s)
      GLOAD16(Bbase + (it << 6) + off[s], (char*)Bs + ldsOff[s]);
    __syncthreads();
#pragma unroll
    for (int ks = 0; ks < 2; ++ks) {
      const int kg = (ks << 2) + (lane >> 4);
      bf16x8 af[4], bfr[4];
#pragma unroll
      for (int mi = 0; mi < 4; ++mi) {
        const int row = (wy << 6) + (mi << 4) + (lane & 15);
        af[mi] = *(const bf16x8*)&As[(row << 6) + ((kg ^ (row & 7)) << 3)];
      }
#pragma unroll
      for (int ni = 0; ni < 4; ++ni) {
        const int col = (wx << 6) + (ni << 4) + (lane & 15);
        bfr[ni] = *(const bf16x8*)&Bs[(col << 6) + ((kg ^ (col & 7)) << 3)];
      }
#pragma unroll
      for (int mi = 0; mi < 4; ++mi)
#pragma unroll
        for (int ni = 0; ni < 4; ++ni)
          acc[mi][ni] = __builtin_amdgcn_mfma_f32_16x16x32_bf16(
              af[mi], bfr[ni], acc[mi][ni], 0, 0, 0);
    }
  }

#pragma unroll
  for (int mi = 0; mi < 4; ++mi) {
#pragma unroll
    for (int ni = 0; ni < 4; ++ni) {
      const int col = n0 + (wx << 6) + (ni << 4) + (lane & 15);
#pragma unroll
      for (int j = 0; j < 4; ++j) {
        const int r = t0 + (wy << 6) + (mi << 4) + ((lane >> 4) << 2) + j;
        out[((size_t)(t_start + r) * NE + be) * NH + col] = acc[mi][ni][j];
      }
    }
  }
}

extern "C" void kernel_launch(void* const* d_in, const int* in_sizes, int n_in,
                              void* d_out, int out_size, void* d_ws, size_t ws_size,
                              hipStream_t stream) {
  const float* x = (const float*)d_in[0];   // [T, E, H] fp32
  const float* wi = (const float*)d_in[1];  // [E, H, I] fp32
  const float* wo = (const float*)d_in[2];  // [E, I, H] fp32
  float* out = (float*)d_out;

  // ws (1.07 GB avail): wiB 64MiB | woB 64MiB | xB [E][T][H] 128MiB | h 256MiB
  uint16_t* wiB = (uint16_t*)d_ws;
  uint16_t* woB = (uint16_t*)((char*)d_ws + 67108864);
  uint16_t* xB = (uint16_t*)((char*)d_ws + 134217728);
  char* rest = (char*)d_ws + 134217728 + (size_t)NE * NT * NH * 2;

  // Full-T single pass (slicing proven -114us in r9 via grid-tail quantization)
  const size_t fixed = 134217728u + (size_t)NE * NT * NH * 2;
  size_t avail = (ws_size > fixed) ? ws_size - fixed : 0;
  int Ts = (int)(avail / ((size_t)NE * NI * 2));
  Ts &= ~127;
  if (Ts > NT) Ts = NT;
  if (Ts < 128) Ts = 128;
  uint16_t* h = (uint16_t*)rest;

  hipLaunchKernelGGL(prep_fused, dim3(24576), dim3(256), 0, stream,
                     wi, wo, x, wiB, woB, xB);

  for (int ts = 0; ts < NT; ts += Ts) {
    int cur = NT - ts;
    if (cur > Ts) cur = Ts;
    const int Mt = cur >> 7;
    hipLaunchKernelGGL(k_gemm1, dim3(Mt * 8 * NE), dim3(256), 0, stream,
                       xB + (size_t)ts * NH, wiB, h, cur);  // xB[e] stride NT!
    hipLaunchKernelGGL(k_gemm2, dim3(Mt * 4 * NE), dim3(256), 0, stream,
                       h, woB, out, ts, cur);
  }
  // NOTE: when Ts == NT (the expected case, ws >= 530 MiB), the xB offset and
  // per-expert stride are consistent (single slice). The loop body runs once.
}

// Round 11
// 549.298 us; speedup vs baseline: 1.4438x; 1.0253x over previous
//
#include <hip/hip_runtime.h>
#include <stdint.h>

#define NE 64
#define NT 2048
#define NH 512
#define NI 1024

typedef __attribute__((ext_vector_type(8))) short bf16x8;
typedef __attribute__((ext_vector_type(4))) float f32x4;

typedef const __attribute__((address_space(1))) void* gptr1_t;
typedef __attribute__((address_space(3))) void* lptr3_t;
#define GLOAD16(g, l) \
  __builtin_amdgcn_global_load_lds((gptr1_t)(const void*)(g), (lptr3_t)(void*)(l), 16, 0, 0)

static __device__ __forceinline__ uint16_t f2bf(float f) {
  uint32_t u = __builtin_bit_cast(uint32_t, f);
  u += 0x7fffu + ((u >> 16) & 1u);
  return (uint16_t)(u >> 16);
}

// erf-based GELU (reference-exact form). r10 A/B: the tanh+__expf variant
// cost +16 VGPR and +19us on gemm1 — erff codegen is cheaper here.
static __device__ __forceinline__ float gelu_erf(float v) {
  return 0.5f * v * (1.0f + erff(v * 0.7071067811865475f));
}

// ---------------------------------------------------------------------------
// Fused prep (one launch, r10-proven ~134us):
//  blocks [0, 8192):      wi[e][512][1024] f32 -> wiB[e][n][k] bf16 (64x64 tr)
//  blocks [8192, 16384):  wo[e][1024][512] f32 -> woB[e][n][k] bf16
//  blocks [16384, 24576): x[t][e][:] f32 -> xB[e][t][:] bf16
// ---------------------------------------------------------------------------
__global__ __launch_bounds__(256)
void prep_fused(const float* __restrict__ wi, const float* __restrict__ wo,
                const float* __restrict__ x, uint16_t* __restrict__ wiB,
                uint16_t* __restrict__ woB, uint16_t* __restrict__ xB) {
  const int bid = blockIdx.x;
  const int tid = threadIdx.x;

  if (bid >= 16384) {  // cast_x section
    const int base = (bid - 16384) << 10;
#pragma unroll
    for (int k = 0; k < 4; ++k) {
      const int c = base + (k << 8) + tid;
      const int hb = c & 63;
      const int e = (c >> 6) & 63;
      const int t = c >> 12;
      const float* ip = x + ((size_t)t * NE + e) * NH + (hb << 3);
      const f32x4 v0 = *(const f32x4*)ip;
      const f32x4 v1 = *(const f32x4*)(ip + 4);
      bf16x8 w;
#pragma unroll
      for (int u = 0; u < 4; ++u) {
        w[u] = (short)f2bf(v0[u]);
        w[u + 4] = (short)f2bf(v1[u]);
      }
      *(bf16x8*)&xB[((size_t)e * NT + t) * NH + (hb << 3)] = w;
    }
    return;
  }

  const float* in;
  uint16_t* out;
  int K, N, k0, n0, e;
  if (bid < 8192) {
    e = bid >> 7;
    const int rem = bid & 127;
    k0 = (rem >> 4) << 6;
    n0 = (rem & 15) << 6;
    in = wi; out = wiB; K = NH; N = NI;
  } else {
    const int id = bid - 8192;
    e = id >> 7;
    const int rem = id & 127;
    k0 = (rem >> 3) << 6;
    n0 = (rem & 7) << 6;
    in = wo; out = woB; K = NI; N = NH;
  }
  __shared__ uint16_t t[64][72];
  const int r = tid >> 2;
  const int c0 = (tid & 3) << 4;
  const float* ip = in + ((size_t)e * K + k0 + r) * N + n0 + c0;
#pragma unroll
  for (int j = 0; j < 16; j += 4) {
    f32x4 v = *(const f32x4*)(ip + j);
#pragma unroll
    for (int u = 0; u < 4; ++u) t[c0 + j + u][r] = f2bf(v[u]);
  }
  __syncthreads();
  uint16_t* op = out + ((size_t)e * N + n0 + r) * K + k0 + c0;
  *(bf16x8*)op = *(const bf16x8*)&t[r][c0];
  *(bf16x8*)(op + 8) = *(const bf16x8*)&t[r][c0 + 8];
}

// ---------------------------------------------------------------------------
// GEMM1 + GELU: h[e,t,i] = gelu( xB[e,t,:] . wi'[e,i,:] ), bf16 out.
// m97 structure (r3/r6-proven best: 213-217us): 128x128x64 tile, single
// 32 KiB LDS buffer, 2 barriers/K-step, both operands via global_load_lds
// with XOR-swizzled SOURCE (LDS dest linear).
// LDS elem (r,k) at r*64 + ((k>>3)^(r&7))*8 + (k&7).
// ---------------------------------------------------------------------------
__global__ __launch_bounds__(256, 4)
void k_gemm1(const uint16_t* __restrict__ xB, const uint16_t* __restrict__ wiB,
             uint16_t* __restrict__ h, int Ts) {
  const int Mt = Ts >> 7;
  const int nwg = gridDim.x;  // Mt*8*64, divisible by 8
  const int wid = (blockIdx.x & 7) * (nwg >> 3) + (blockIdx.x >> 3);
  const int bn = wid & 7;
  const int bm = (wid >> 3) % Mt;
  const int be = wid / (Mt << 3);
  const int t0 = bm << 7, n0 = bn << 7;

  __shared__ __align__(16) uint16_t As[8192];
  __shared__ __align__(16) uint16_t Bs[8192];

  const int tid = threadIdx.x, lane = tid & 63;
  const int wy = (tid >> 7) & 1, wx = (tid >> 6) & 1;

  const uint16_t* Abase = xB + ((size_t)be * Ts + t0) * NH;
  const uint16_t* Bbase = wiB + ((size_t)be * NI + n0) * NH;

  int off[4], ldsOff[4];
#pragma unroll
  for (int s = 0; s < 4; ++s) {
    const int c = (s << 8) + tid;
    const int rr = c >> 3, kgs = c & 7;
    off[s] = (rr << 9) + ((kgs ^ (rr & 7)) << 3);  // row stride NH=512
    ldsOff[s] = c << 4;
  }

  f32x4 acc[4][4];
#pragma unroll
  for (int i = 0; i < 4; ++i)
#pragma unroll
    for (int j = 0; j < 4; ++j) acc[i][j] = (f32x4){0.f, 0.f, 0.f, 0.f};

  const int KIT = NH >> 6;  // 8
  for (int it = 0; it < KIT; ++it) {
    __syncthreads();
#pragma unroll
    for (int s = 0; s < 4; ++s)
      GLOAD16(Abase + (it << 6) + off[s], (char*)As + ldsOff[s]);
#pragma unroll
    for (int s = 0; s < 4; ++s)
      GLOAD16(Bbase + (it << 6) + off[s], (char*)Bs + ldsOff[s]);
    __syncthreads();
#pragma unroll
    for (int ks = 0; ks < 2; ++ks) {
      const int kg = (ks << 2) + (lane >> 4);
      bf16x8 af[4], bfr[4];
#pragma unroll
      for (int mi = 0; mi < 4; ++mi) {
        const int row = (wy << 6) + (mi << 4) + (lane & 15);
        af[mi] = *(const bf16x8*)&As[(row << 6) + ((kg ^ (row & 7)) << 3)];
      }
#pragma unroll
      for (int ni = 0; ni < 4; ++ni) {
        const int col = (wx << 6) + (ni << 4) + (lane & 15);
        bfr[ni] = *(const bf16x8*)&Bs[(col << 6) + ((kg ^ (col & 7)) << 3)];
      }
#pragma unroll
      for (int mi = 0; mi < 4; ++mi)
#pragma unroll
        for (int ni = 0; ni < 4; ++ni)
          acc[mi][ni] = __builtin_amdgcn_mfma_f32_16x16x32_bf16(
              af[mi], bfr[ni], acc[mi][ni], 0, 0, 0);
    }
  }

#pragma unroll
  for (int mi = 0; mi < 4; ++mi) {
#pragma unroll
    for (int ni = 0; ni < 4; ++ni) {
      const int col = n0 + (wx << 6) + (ni << 4) + (lane & 15);
#pragma unroll
      for (int j = 0; j < 4; ++j) {
        const int r = t0 + (wy << 6) + (mi << 4) + ((lane >> 4) << 2) + j;
        h[((size_t)be * Ts + r) * NI + col] = f2bf(gelu_erf(acc[mi][ni][j]));
      }
    }
  }
}

// ---------------------------------------------------------------------------
// GEMM2: out[t,e,hc] = h[e,t,:] . wo'[e,hc,:], fp32 out (r3-proven, ~195us).
// ---------------------------------------------------------------------------
__global__ __launch_bounds__(256, 3)
void k_gemm2(const uint16_t* __restrict__ hA, const uint16_t* __restrict__ woB,
             float* __restrict__ out, int t_start, int Ts) {
  const int Mt = Ts >> 7;
  const int nwg = gridDim.x;  // Mt*4*64
  const int wid = (blockIdx.x & 7) * (nwg >> 3) + (blockIdx.x >> 3);
  const int bn = wid & 3;
  const int bm = (wid >> 2) % Mt;
  const int be = wid / (Mt << 2);
  const int t0 = bm << 7, n0 = bn << 7;

  __shared__ __align__(16) uint16_t As[8192];
  __shared__ __align__(16) uint16_t Bs[8192];

  const int tid = threadIdx.x, lane = tid & 63;
  const int wy = (tid >> 7) & 1, wx = (tid >> 6) & 1;

  const uint16_t* Abase = hA + ((size_t)be * Ts + t0) * NI;
  const uint16_t* Bbase = woB + ((size_t)be * NH + n0) * NI;

  int off[4], ldsOff[4];
#pragma unroll
  for (int s = 0; s < 4; ++s) {
    const int c = (s << 8) + tid;
    const int rr = c >> 3, kgs = c & 7;
    off[s] = (rr << 10) + ((kgs ^ (rr & 7)) << 3);  // row stride NI=1024
    ldsOff[s] = c << 4;
  }

  f32x4 acc[4][4];
#pragma unroll
  for (int i = 0; i < 4; ++i)
#pragma unroll
    for (int j = 0; j < 4; ++j) acc[i][j] = (f32x4){0.f, 0.f, 0.f, 0.f};

  const int KIT = NI >> 6;  // 16
  for (int it = 0; it < KIT; ++it) {
    __syncthreads();
#pragma unroll
    for (int s = 0; s < 4; ++s)
      GLOAD16(Abase + (it << 6) + off[s], (char*)As + ldsOff[s]);
#pragma unroll
    for (int s = 0; s < 4; ++s)
      GLOAD16(Bbase + (it << 6) + off[s], (char*)Bs + ldsOff[s]);
    __syncthreads();
#pragma unroll
    for (int ks = 0; ks < 2; ++ks) {
      const int kg = (ks << 2) + (lane >> 4);
      bf16x8 af[4], bfr[4];
#pragma unroll
      for (int mi = 0; mi < 4; ++mi) {
        const int row = (wy << 6) + (mi << 4) + (lane & 15);
        af[mi] = *(const bf16x8*)&As[(row << 6) + ((kg ^ (row & 7)) << 3)];
      }
#pragma unroll
      for (int ni = 0; ni < 4; ++ni) {
        const int col = (wx << 6) + (ni << 4) + (lane & 15);
        bfr[ni] = *(const bf16x8*)&Bs[(col << 6) + ((kg ^ (col & 7)) << 3)];
      }
#pragma unroll
      for (int mi = 0; mi < 4; ++mi)
#pragma unroll
        for (int ni = 0; ni < 4; ++ni)
          acc[mi][ni] = __builtin_amdgcn_mfma_f32_16x16x32_bf16(
              af[mi], bfr[ni], acc[mi][ni], 0, 0, 0);
    }
  }

#pragma unroll
  for (int mi = 0; mi < 4; ++mi) {
#pragma unroll
    for (int ni = 0; ni < 4; ++ni) {
      const int col = n0 + (wx << 6) + (ni << 4) + (lane & 15);
#pragma unroll
      for (int j = 0; j < 4; ++j) {
        const int r = t0 + (wy << 6) + (mi << 4) + ((lane >> 4) << 2) + j;
        out[((size_t)(t_start + r) * NE + be) * NH + col] = acc[mi][ni][j];
      }
    }
  }
}

extern "C" void kernel_launch(void* const* d_in, const int* in_sizes, int n_in,
                              void* d_out, int out_size, void* d_ws, size_t ws_size,
                              hipStream_t stream) {
  const float* x = (const float*)d_in[0];   // [T, E, H] fp32
  const float* wi = (const float*)d_in[1];  // [E, H, I] fp32
  const float* wo = (const float*)d_in[2];  // [E, I, H] fp32
  float* out = (float*)d_out;

  // ws (~1.07 GB): wiB 64MiB | woB 64MiB | xB [E][T][H] 128MiB | h 256MiB
  uint16_t* wiB = (uint16_t*)d_ws;
  uint16_t* woB = (uint16_t*)((char*)d_ws + 67108864);
  uint16_t* xB = (uint16_t*)((char*)d_ws + 134217728);
  char* rest = (char*)d_ws + 134217728 + (size_t)NE * NT * NH * 2;

  const size_t fixed = 134217728u + (size_t)NE * NT * NH * 2;
  size_t avail = (ws_size > fixed) ? ws_size - fixed : 0;
  int Ts = (int)(avail / ((size_t)NE * NI * 2));
  Ts &= ~127;
  if (Ts > NT) Ts = NT;
  if (Ts < 128) Ts = 128;
  uint16_t* h = (uint16_t*)rest;

  hipLaunchKernelGGL(prep_fused, dim3(24576), dim3(256), 0, stream,
                     wi, wo, x, wiB, woB, xB);

  for (int ts = 0; ts < NT; ts += Ts) {
    int cur = NT - ts;
    if (cur > Ts) cur = Ts;
    const int Mt = cur >> 7;
    hipLaunchKernelGGL(k_gemm1, dim3(Mt * 8 * NE), dim3(256), 0, stream,
                       xB + (size_t)ts * NH, wiB, h, cur);
    hipLaunchKernelGGL(k_gemm2, dim3(Mt * 4 * NE), dim3(256), 0, stream,
                       h, woB, out, ts, cur);
  }
}